// Round 2
// baseline (276.764 us; speedup 1.0000x reference)
//
#include <hip/hip_runtime.h>
#include <stdint.h>

#define BB     32
#define NN     2000
#define TOPK_  110
#define SORTN  2048
#define NGRP   400

// ---------------------------------------------------------------------------
// Kernel 1: diag[b,n] = softmax(Q K^T / sqrt(5))[n,n]  (only the diagonal!)
// grid (8 chunks, 32 batches), block 128, 2 rows per thread.
// Each block stages the full K[b] (2000x5) into LDS split as float4 + float
// (40 KB total -> 4 blocks/CU residency). All K reads are wave-uniform
// broadcasts (bank-conflict-free).
// ---------------------------------------------------------------------------
__global__ __launch_bounds__(128) void k_diag(
    const float* __restrict__ in_mat,                       // [B,N,3]
    const float* __restrict__ Wi, const float* __restrict__ bi,
    const float* __restrict__ Wq, const float* __restrict__ bq,
    const float* __restrict__ Wk, const float* __restrict__ bk,
    float* __restrict__ diag_out)                           // [B,N] in d_ws
{
    __shared__ float4 Ks4[SORTN];    // K[:,0..3]  (32 KB)
    __shared__ float  Ks1[SORTN];    // K[:,4]     ( 8 KB)

    const int b     = blockIdx.y;
    const int chunk = blockIdx.x;
    const int t     = threadIdx.x;
    const float* inb = in_mat + (size_t)b * NN * 3;

    // --- staging weights (uniform loads, cached) ---
    float wi[15], bi_[5], wk[25], bk_[5];
#pragma unroll
    for (int i = 0; i < 15; ++i) wi[i] = Wi[i];
#pragma unroll
    for (int i = 0; i < 5; ++i)  bi_[i] = bi[i];
#pragma unroll
    for (int i = 0; i < 25; ++i) wk[i] = Wk[i];
#pragma unroll
    for (int i = 0; i < 5; ++i)  bk_[i] = bk[i];

    // --- stage K for the whole batch into LDS (16 rows per thread) ---
#pragma unroll
    for (int r = 0; r < SORTN / 128; ++r) {
        const int n = r * 128 + t;
        float k[5] = {0.f, 0.f, 0.f, 0.f, 0.f};
        if (n < NN) {
            const float p0 = inb[n * 3 + 0];
            const float p1 = inb[n * 3 + 1];
            const float p2 = inb[n * 3 + 2];
            float x[5];
#pragma unroll
            for (int j = 0; j < 5; ++j)
                x[j] = p0 * wi[j] + p1 * wi[5 + j] + p2 * wi[10 + j] + bi_[j];
#pragma unroll
            for (int j = 0; j < 5; ++j) {
                float s = bk_[j];
#pragma unroll
                for (int i = 0; i < 5; ++i) s += x[i] * wk[i * 5 + j];
                k[j] = s;
            }
        }
        Ks4[n] = make_float4(k[0], k[1], k[2], k[3]);
        Ks1[n] = k[4];
    }
    __syncthreads();

    // --- this thread's two query rows ---
    const int n0 = chunk * 256 + t;          // always < 2000 (max 1919)
    const int n1 = n0 + 128;                 // may exceed in last chunk
    const bool v1 = (n1 < NN);

    float wq[25], bq_[5];
#pragma unroll
    for (int i = 0; i < 25; ++i) wq[i] = Wq[i];
#pragma unroll
    for (int i = 0; i < 5; ++i)  bq_[i] = bq[i];

    float q0[5], q1[5];
    {
        const float p0 = inb[n0 * 3 + 0], p1 = inb[n0 * 3 + 1], p2 = inb[n0 * 3 + 2];
        float x[5];
#pragma unroll
        for (int j = 0; j < 5; ++j)
            x[j] = p0 * wi[j] + p1 * wi[5 + j] + p2 * wi[10 + j] + bi_[j];
#pragma unroll
        for (int j = 0; j < 5; ++j) {
            float s = bq_[j];
#pragma unroll
            for (int i = 0; i < 5; ++i) s += x[i] * wq[i * 5 + j];
            q0[j] = s;
        }
    }
    if (v1) {
        const float p0 = inb[n1 * 3 + 0], p1 = inb[n1 * 3 + 1], p2 = inb[n1 * 3 + 2];
        float x[5];
#pragma unroll
        for (int j = 0; j < 5; ++j)
            x[j] = p0 * wi[j] + p1 * wi[5 + j] + p2 * wi[10 + j] + bi_[j];
#pragma unroll
        for (int j = 0; j < 5; ++j) {
            float s = bq_[j];
#pragma unroll
            for (int i = 0; i < 5; ++i) s += x[i] * wq[i * 5 + j];
            q1[j] = s;
        }
    } else {
#pragma unroll
        for (int j = 0; j < 5; ++j) q1[j] = 0.f;
    }

    const float scale = 0.44721359549995793f;   // 1/sqrt(5)

    // diagonal scores
    const float4 kd0 = Ks4[n0];
    float snn0 = (q0[0] * kd0.x + q0[1] * kd0.y + q0[2] * kd0.z +
                  q0[3] * kd0.w + q0[4] * Ks1[n0]) * scale;
    float snn1 = 0.f;
    if (v1) {
        const float4 kd1 = Ks4[n1];
        snn1 = (q1[0] * kd1.x + q1[1] * kd1.y + q1[2] * kd1.z +
                q1[3] * kd1.w + q1[4] * Ks1[n1]) * scale;
    }

    // single-pass softmax denominator (scores bounded, no max-subtract needed;
    // diag only feeds an argmax over group sums, ulp noise is harmless)
    float sum0 = 0.f, sum1 = 0.f;
#pragma unroll 4
    for (int m = 0; m < NN; ++m) {
        const float4 kv = Ks4[m];
        const float  k4 = Ks1[m];
        const float s0 = (q0[0] * kv.x + q0[1] * kv.y + q0[2] * kv.z +
                          q0[3] * kv.w + q0[4] * k4) * scale;
        const float s1 = (q1[0] * kv.x + q1[1] * kv.y + q1[2] * kv.z +
                          q1[3] * kv.w + q1[4] * k4) * scale;
        sum0 += __expf(s0);
        sum1 += __expf(s1);
    }

    diag_out[b * NN + n0] = __expf(snn0) / sum0;
    if (v1) diag_out[b * NN + n1] = __expf(snn1) / sum1;
}

// ---------------------------------------------------------------------------
// Kernel 2: per batch — group sums, argmax group, centroid, distances,
// top-110 by ascending distance (tie -> lower index), gather points.
// grid 32, block 256.
// ---------------------------------------------------------------------------
__global__ __launch_bounds__(256) void k_select(
    const float* __restrict__ in_mat,     // [B,N,3]
    const float* __restrict__ diag,       // [B,N]
    float* __restrict__ out)              // [B,110,3]
{
    __shared__ float              gsum[NGRP];
    __shared__ unsigned long long keys[SORTN];
    __shared__ float              red_v[256];
    __shared__ int                red_i[256];
    __shared__ float              centroid[3];

    const int b = blockIdx.x;
    const int t = threadIdx.x;
    const float* dg  = diag + (size_t)b * NN;
    const float* inb = in_mat + (size_t)b * NN * 3;

    // --- group sums of 5 consecutive diag values (reference order) ---
    for (int g = t; g < NGRP; g += 256) {
        float s = dg[g * 5 + 0];
        s += dg[g * 5 + 1];
        s += dg[g * 5 + 2];
        s += dg[g * 5 + 3];
        s += dg[g * 5 + 4];
        gsum[g] = s;
    }
    __syncthreads();

    // --- argmax (first max wins, like jnp.argmax) ---
    float bv = -INFINITY; int bidx = 0x7fffffff;
    for (int g = t; g < NGRP; g += 256) {
        const float v = gsum[g];
        if (v > bv || (v == bv && g < bidx)) { bv = v; bidx = g; }
    }
    red_v[t] = bv; red_i[t] = bidx;
    __syncthreads();
    for (int s = 128; s > 0; s >>= 1) {
        if (t < s) {
            const float v = red_v[t + s]; const int i = red_i[t + s];
            if (v > red_v[t] || (v == red_v[t] && i < red_i[t])) {
                red_v[t] = v; red_i[t] = i;
            }
        }
        __syncthreads();
    }

    // --- centroid of winning group (bit-exact numpy mean: rn adds, /5) ---
    if (t == 0) {
        const int base = red_i[0] * 5;
#pragma unroll
        for (int d = 0; d < 3; ++d) {
            float s = inb[(base + 0) * 3 + d];
            s = __fadd_rn(s, inb[(base + 1) * 3 + d]);
            s = __fadd_rn(s, inb[(base + 2) * 3 + d]);
            s = __fadd_rn(s, inb[(base + 3) * 3 + d]);
            s = __fadd_rn(s, inb[(base + 4) * 3 + d]);
            centroid[d] = __fdiv_rn(s, 5.0f);
        }
    }
    __syncthreads();

    const float c0 = centroid[0], c1 = centroid[1], c2 = centroid[2];

    // --- distances -> sortable keys (dist_bits<<32 | index) ---
    for (int n = t; n < SORTN; n += 256) {
        unsigned long long key;
        if (n < NN) {
            const float dx = inb[n * 3 + 0] - c0;
            const float dy = inb[n * 3 + 1] - c1;
            const float dz = inb[n * 3 + 2] - c2;
            // no FMA contraction: bit-exact vs np.linalg.norm ((x2+y2)+z2)
            const float d2 = __fadd_rn(__fadd_rn(__fmul_rn(dx, dx),
                                                 __fmul_rn(dy, dy)),
                                       __fmul_rn(dz, dz));
            const float dist = __fsqrt_rn(d2);
            key = ((unsigned long long)__float_as_uint(dist) << 32) |
                  (unsigned int)n;
        } else {
            key = 0xFFFFFFFFFFFFFFFFull;
        }
        keys[n] = key;
    }
    __syncthreads();

    // --- bitonic sort ascending over 2048 u64 keys ---
    for (int k = 2; k <= SORTN; k <<= 1) {
        for (int j = k >> 1; j > 0; j >>= 1) {
            for (int idx = t; idx < SORTN; idx += 256) {
                const int ixj = idx ^ j;
                if (ixj > idx) {
                    const unsigned long long a  = keys[idx];
                    const unsigned long long bb = keys[ixj];
                    const bool up = ((idx & k) == 0);
                    if ((up && a > bb) || (!up && a < bb)) {
                        keys[idx] = bb; keys[ixj] = a;
                    }
                }
            }
            __syncthreads();
        }
    }

    // --- gather the 110 closest points (exact copies of in_mat rows) ---
    for (int kk = t; kk < TOPK_; kk += 256) {
        const int n = (int)(unsigned int)(keys[kk] & 0xFFFFFFFFull);
        out[((size_t)b * TOPK_ + kk) * 3 + 0] = inb[n * 3 + 0];
        out[((size_t)b * TOPK_ + kk) * 3 + 1] = inb[n * 3 + 1];
        out[((size_t)b * TOPK_ + kk) * 3 + 2] = inb[n * 3 + 2];
    }
}

// ---------------------------------------------------------------------------
extern "C" void kernel_launch(void* const* d_in, const int* in_sizes, int n_in,
                              void* d_out, int out_size, void* d_ws, size_t ws_size,
                              hipStream_t stream) {
    const float* in_mat = (const float*)d_in[0];
    const float* Wi = (const float*)d_in[1];
    const float* bi = (const float*)d_in[2];
    const float* Wq = (const float*)d_in[3];
    const float* bq = (const float*)d_in[4];
    const float* Wk = (const float*)d_in[5];
    const float* bk = (const float*)d_in[6];
    // Wv, bv, Wo, bo (d_in[7..10]) are dead code in the reference.

    float* diag = (float*)d_ws;               // B*N floats = 256 KB
    float* out  = (float*)d_out;              // B*110*3 floats

    dim3 g1(8, BB);
    k_diag<<<g1, 128, 0, stream>>>(in_mat, Wi, bi, Wq, bq, Wk, bk, diag);
    k_select<<<BB, 256, 0, stream>>>(in_mat, diag, out);
}

// Round 3
// 154.696 us; speedup vs baseline: 1.7891x; 1.7891x over previous
//
#include <hip/hip_runtime.h>
#include <stdint.h>

#define BB     32
#define NN     2000
#define TOPK_  110
#define SORTN  2048
#define NGRP   400

// ---------------------------------------------------------------------------
// Kernel 1: diag[b,n] = softmax(Q K^T / sqrt(5))[n,n]  (only the diagonal!)
// grid (32 row-chunks, 32 batches), block 512 (8 waves).
// Block owns 64 rows (one per lane). Wave w sums exp over m-chunk
// [w*250, w*250+250) -> all 64 lanes broadcast-read the same Ks[m].
// Partials reduced via LDS in fixed wave order (deterministic).
// ---------------------------------------------------------------------------
__global__ __launch_bounds__(512) void k_diag(
    const float* __restrict__ in_mat,                       // [B,N,3]
    const float* __restrict__ Wi, const float* __restrict__ bi,
    const float* __restrict__ Wq, const float* __restrict__ bq,
    const float* __restrict__ Wk, const float* __restrict__ bk,
    float* __restrict__ diag_out)                           // [B,N] in d_ws
{
    __shared__ float4 Ks4[SORTN];       // K[:,0..3]  (32 KB)
    __shared__ float  Ks1[SORTN];       // K[:,4]     ( 8 KB)
    __shared__ float  partial[8][64];   // per-wave exp-sum partials (2 KB)

    const int b     = blockIdx.y;
    const int chunk = blockIdx.x;
    const int t     = threadIdx.x;
    const float* inb = in_mat + (size_t)b * NN * 3;

    // --- stage K for the whole batch into LDS (4 rows per thread) ---
    {
        float wi[15], bi_[5], wk[25], bk_[5];
#pragma unroll
        for (int i = 0; i < 15; ++i) wi[i] = Wi[i];
#pragma unroll
        for (int i = 0; i < 5; ++i)  bi_[i] = bi[i];
#pragma unroll
        for (int i = 0; i < 25; ++i) wk[i] = Wk[i];
#pragma unroll
        for (int i = 0; i < 5; ++i)  bk_[i] = bk[i];

#pragma unroll
        for (int r = 0; r < SORTN / 512; ++r) {
            const int n = r * 512 + t;
            float k[5] = {0.f, 0.f, 0.f, 0.f, 0.f};
            if (n < NN) {
                const float p0 = inb[n * 3 + 0];
                const float p1 = inb[n * 3 + 1];
                const float p2 = inb[n * 3 + 2];
                float x[5];
#pragma unroll
                for (int j = 0; j < 5; ++j)
                    x[j] = p0 * wi[j] + p1 * wi[5 + j] + p2 * wi[10 + j] + bi_[j];
#pragma unroll
                for (int j = 0; j < 5; ++j) {
                    float s = bk_[j];
#pragma unroll
                    for (int i = 0; i < 5; ++i) s += x[i] * wk[i * 5 + j];
                    k[j] = s;
                }
            }
            Ks4[n] = make_float4(k[0], k[1], k[2], k[3]);
            Ks1[n] = k[4];
        }
    }

    // --- this lane's query row, prescaled by (1/sqrt(5))*log2(e) ---
    const int wid  = t >> 6;
    const int lane = t & 63;
    const int row  = chunk * 64 + lane;
    const bool valid = (row < NN);

    float q[5] = {0.f, 0.f, 0.f, 0.f, 0.f};
    if (valid) {
        float wi[15], bi_[5], wq[25], bq_[5];
#pragma unroll
        for (int i = 0; i < 15; ++i) wi[i] = Wi[i];
#pragma unroll
        for (int i = 0; i < 5; ++i)  bi_[i] = bi[i];
#pragma unroll
        for (int i = 0; i < 25; ++i) wq[i] = Wq[i];
#pragma unroll
        for (int i = 0; i < 5; ++i)  bq_[i] = bq[i];

        const float p0 = inb[row * 3 + 0];
        const float p1 = inb[row * 3 + 1];
        const float p2 = inb[row * 3 + 2];
        float x[5];
#pragma unroll
        for (int j = 0; j < 5; ++j)
            x[j] = p0 * wi[j] + p1 * wi[5 + j] + p2 * wi[10 + j] + bi_[j];
        // scale * log2(e): softmax(s/sqrt5) == exp2-based with this prefactor
        const float pf = 0.44721359549995793f * 1.4426950408889634f;
#pragma unroll
        for (int j = 0; j < 5; ++j) {
            float s = bq_[j];
#pragma unroll
            for (int i = 0; i < 5; ++i) s += x[i] * wq[i * 5 + j];
            q[j] = s * pf;
        }
    }
    __syncthreads();

    // --- exp-sum over this wave's m-chunk (broadcast LDS reads) ---
    float acc0 = 0.f, acc1 = 0.f;
    const int m0 = wid * (NN / 8);
#pragma unroll 2
    for (int m = m0; m < m0 + NN / 8; m += 2) {
        const float4 a = Ks4[m];     const float a4 = Ks1[m];
        const float4 c = Ks4[m + 1]; const float c4 = Ks1[m + 1];
        const float s0 = q[0] * a.x + q[1] * a.y + q[2] * a.z +
                         q[3] * a.w + q[4] * a4;
        const float s1 = q[0] * c.x + q[1] * c.y + q[2] * c.z +
                         q[3] * c.w + q[4] * c4;
        acc0 += __builtin_amdgcn_exp2f(s0);
        acc1 += __builtin_amdgcn_exp2f(s1);
    }
    partial[wid][lane] = acc0 + acc1;
    __syncthreads();

    // --- wave 0 combines partials (fixed order) and writes diag ---
    if (wid == 0 && valid) {
        float sum = partial[0][lane];
#pragma unroll
        for (int w = 1; w < 8; ++w) sum += partial[w][lane];
        const float4 kd = Ks4[row];
        const float snn2 = q[0] * kd.x + q[1] * kd.y + q[2] * kd.z +
                           q[3] * kd.w + q[4] * Ks1[row];
        diag_out[b * NN + row] = __builtin_amdgcn_exp2f(snn2) / sum;
    }
}

// ---------------------------------------------------------------------------
// Kernel 2: per batch — group sums, argmax group, centroid, distances,
// top-110 by ascending distance (tie -> lower index), gather points.
// grid 32, block 1024 (16 waves).
// ---------------------------------------------------------------------------
__global__ __launch_bounds__(1024) void k_select(
    const float* __restrict__ in_mat,     // [B,N,3]
    const float* __restrict__ diag,       // [B,N]
    float* __restrict__ out)              // [B,110,3]
{
    __shared__ float              gsum[NGRP];
    __shared__ unsigned long long keys[SORTN];
    __shared__ float              red_v[1024];
    __shared__ int                red_i[1024];
    __shared__ float              centroid[3];

    const int b = blockIdx.x;
    const int t = threadIdx.x;
    const float* dg  = diag + (size_t)b * NN;
    const float* inb = in_mat + (size_t)b * NN * 3;

    // --- group sums of 5 consecutive diag values (reference order) ---
    if (t < NGRP) {
        float s = dg[t * 5 + 0];
        s += dg[t * 5 + 1];
        s += dg[t * 5 + 2];
        s += dg[t * 5 + 3];
        s += dg[t * 5 + 4];
        gsum[t] = s;
    }
    __syncthreads();

    // --- argmax (first max wins, like jnp.argmax) ---
    red_v[t] = (t < NGRP) ? gsum[t] : -INFINITY;
    red_i[t] = (t < NGRP) ? t : 0x7fffffff;
    __syncthreads();
    for (int s = 512; s > 0; s >>= 1) {
        if (t < s) {
            const float v = red_v[t + s]; const int i = red_i[t + s];
            if (v > red_v[t] || (v == red_v[t] && i < red_i[t])) {
                red_v[t] = v; red_i[t] = i;
            }
        }
        __syncthreads();
    }

    // --- centroid of winning group (bit-exact numpy mean: rn adds, /5) ---
    if (t == 0) {
        const int base = red_i[0] * 5;
#pragma unroll
        for (int d = 0; d < 3; ++d) {
            float s = inb[(base + 0) * 3 + d];
            s = __fadd_rn(s, inb[(base + 1) * 3 + d]);
            s = __fadd_rn(s, inb[(base + 2) * 3 + d]);
            s = __fadd_rn(s, inb[(base + 3) * 3 + d]);
            s = __fadd_rn(s, inb[(base + 4) * 3 + d]);
            centroid[d] = __fdiv_rn(s, 5.0f);
        }
    }
    __syncthreads();

    const float c0 = centroid[0], c1 = centroid[1], c2 = centroid[2];

    // --- distances -> sortable keys (dist_bits<<32 | index) ---
    for (int n = t; n < SORTN; n += 1024) {
        unsigned long long key;
        if (n < NN) {
            const float dx = inb[n * 3 + 0] - c0;
            const float dy = inb[n * 3 + 1] - c1;
            const float dz = inb[n * 3 + 2] - c2;
            // no FMA contraction: bit-exact vs np.linalg.norm ((x2+y2)+z2)
            const float d2 = __fadd_rn(__fadd_rn(__fmul_rn(dx, dx),
                                                 __fmul_rn(dy, dy)),
                                       __fmul_rn(dz, dz));
            const float dist = __fsqrt_rn(d2);
            key = ((unsigned long long)__float_as_uint(dist) << 32) |
                  (unsigned int)n;
        } else {
            key = 0xFFFFFFFFFFFFFFFFull;
        }
        keys[n] = key;
    }
    __syncthreads();

    // --- bitonic sort ascending over 2048 u64 keys ---
    for (int k = 2; k <= SORTN; k <<= 1) {
        for (int j = k >> 1; j > 0; j >>= 1) {
            for (int idx = t; idx < SORTN; idx += 1024) {
                const int ixj = idx ^ j;
                if (ixj > idx) {
                    const unsigned long long a  = keys[idx];
                    const unsigned long long bb = keys[ixj];
                    const bool up = ((idx & k) == 0);
                    if ((up && a > bb) || (!up && a < bb)) {
                        keys[idx] = bb; keys[ixj] = a;
                    }
                }
            }
            __syncthreads();
        }
    }

    // --- gather the 110 closest points (exact copies of in_mat rows) ---
    if (t < TOPK_) {
        const int n = (int)(unsigned int)(keys[t] & 0xFFFFFFFFull);
        out[((size_t)b * TOPK_ + t) * 3 + 0] = inb[n * 3 + 0];
        out[((size_t)b * TOPK_ + t) * 3 + 1] = inb[n * 3 + 1];
        out[((size_t)b * TOPK_ + t) * 3 + 2] = inb[n * 3 + 2];
    }
}

// ---------------------------------------------------------------------------
extern "C" void kernel_launch(void* const* d_in, const int* in_sizes, int n_in,
                              void* d_out, int out_size, void* d_ws, size_t ws_size,
                              hipStream_t stream) {
    const float* in_mat = (const float*)d_in[0];
    const float* Wi = (const float*)d_in[1];
    const float* bi = (const float*)d_in[2];
    const float* Wq = (const float*)d_in[3];
    const float* bq = (const float*)d_in[4];
    const float* Wk = (const float*)d_in[5];
    const float* bk = (const float*)d_in[6];
    // Wv, bv, Wo, bo (d_in[7..10]) are dead code in the reference.

    float* diag = (float*)d_ws;               // B*N floats = 256 KB
    float* out  = (float*)d_out;              // B*110*3 floats

    dim3 g1(32, BB);                          // (row-chunks, batches)
    k_diag<<<g1, 512, 0, stream>>>(in_mat, Wi, bi, Wq, bq, Wk, bk, diag);
    k_select<<<BB, 1024, 0, stream>>>(in_mat, diag, out);
}

// Round 4
// 104.569 us; speedup vs baseline: 2.6467x; 1.4794x over previous
//
#include <hip/hip_runtime.h>
#include <stdint.h>

#define BB     32
#define NN     2000
#define TOPK_  110
#define NBIN   2048

// ---------------------------------------------------------------------------
// Kernel 1: diag[b,n] = softmax(Q K^T / sqrt(5))[n,n]  via the bilinear form
//   s(n,m) = p_n^T G p_m + u.p_n + v.p_m + w   (G = (WiWq)(WiWk)^T, 3x3)
// The u.p_n + w term cancels in the softmax ratio, so:
//   exponent(n,m) = g_n . p_m + b_m,   g_n = pf*G^T p_n,  b_m = pf*(v.p_m)
// grid (8 row-chunks, 32 batches), block 1024 (16 waves).
// Block owns 256 rows: each lane carries 4 rows (one LDS read serves 4 rows).
// Wave w sums exp2 over m-chunk [w*125, (w+1)*125).
// ---------------------------------------------------------------------------
__global__ __launch_bounds__(1024) void k_diag(
    const float* __restrict__ in_mat,                       // [B,N,3]
    const float* __restrict__ Wi, const float* __restrict__ bi,
    const float* __restrict__ Wq, const float* __restrict__ bq,
    const float* __restrict__ Wk, const float* __restrict__ bk,
    float* __restrict__ diag_out)                           // [B,N] in d_ws
{
    __shared__ float4 Ps[2048];          // (p.x, p.y, p.z, b_m)   32 KB
    __shared__ float  partial[16][256];  // per-wave exp-sums      16 KB

    const int b     = blockIdx.y;
    const int chunk = blockIdx.x;
    const int t     = threadIdx.x;
    const float* inb = in_mat + (size_t)b * NN * 3;

    // --- fold weights: G' = pf * (WiWq)(WiWk)^T, v' = pf * cq (WiWk)^T ---
    // (uniform inputs -> compiler scalarizes; redundant per-thread is cheap)
    const float pf = 0.44721359549995793f * 1.4426950408889634f; // 1/sqrt5*log2e
    float Mq[15], Mk[15], cq[5];
#pragma unroll
    for (int d = 0; d < 5; ++d) {
        float s = bq[d];
#pragma unroll
        for (int k = 0; k < 5; ++k) s += bi[k] * Wq[k * 5 + d];
        cq[d] = s;
    }
#pragma unroll
    for (int i = 0; i < 3; ++i)
#pragma unroll
        for (int d = 0; d < 5; ++d) {
            float sq = 0.f, sk = 0.f;
#pragma unroll
            for (int k = 0; k < 5; ++k) {
                sq += Wi[i * 5 + k] * Wq[k * 5 + d];
                sk += Wi[i * 5 + k] * Wk[k * 5 + d];
            }
            Mq[i * 5 + d] = sq;
            Mk[i * 5 + d] = sk;
        }
    float ck[5];
#pragma unroll
    for (int d = 0; d < 5; ++d) {
        float s = bk[d];
#pragma unroll
        for (int k = 0; k < 5; ++k) s += bi[k] * Wk[k * 5 + d];
        ck[d] = s;
    }
    (void)ck; // ck enters only the cancelled terms
    float Gp[3][3], vp[3];
#pragma unroll
    for (int i = 0; i < 3; ++i)
#pragma unroll
        for (int j = 0; j < 3; ++j) {
            float s = 0.f;
#pragma unroll
            for (int d = 0; d < 5; ++d) s += Mq[i * 5 + d] * Mk[j * 5 + d];
            Gp[i][j] = s * pf;
        }
#pragma unroll
    for (int j = 0; j < 3; ++j) {
        float s = 0.f;
#pragma unroll
        for (int d = 0; d < 5; ++d) s += cq[d] * Mk[j * 5 + d];
        vp[j] = s * pf;
    }

    // --- stage all 2000 points (+ their b_m) into LDS ---
#pragma unroll
    for (int r = 0; r < 2; ++r) {
        const int n = r * 1024 + t;
        float4 e = make_float4(0.f, 0.f, 0.f, 0.f);
        if (n < NN) {
            const float p0 = inb[n * 3 + 0];
            const float p1 = inb[n * 3 + 1];
            const float p2 = inb[n * 3 + 2];
            e = make_float4(p0, p1, p2, vp[0] * p0 + vp[1] * p1 + vp[2] * p2);
        }
        Ps[n] = e;
    }

    // --- this lane's 4 query rows: g_r = pf * G^T p_r ---
    const int wid  = t >> 6;
    const int lane = t & 63;
    float g[4][3];
#pragma unroll
    for (int r = 0; r < 4; ++r) {
        const int row = chunk * 256 + r * 64 + lane;
        float p0 = 0.f, p1 = 0.f, p2 = 0.f;
        if (row < NN) {
            p0 = inb[row * 3 + 0];
            p1 = inb[row * 3 + 1];
            p2 = inb[row * 3 + 2];
        }
#pragma unroll
        for (int j = 0; j < 3; ++j)
            g[r][j] = p0 * Gp[0][j] + p1 * Gp[1][j] + p2 * Gp[2][j];
    }
    __syncthreads();

    // --- exp2-sum over this wave's m-chunk (1 b128 read serves 4 rows) ---
    float acc[4] = {0.f, 0.f, 0.f, 0.f};
    const int m0 = wid * (NN / 16);
#pragma unroll 5
    for (int m = m0; m < m0 + NN / 16; ++m) {
        const float4 P = Ps[m];
#pragma unroll
        for (int r = 0; r < 4; ++r) {
            const float e = fmaf(g[r][0], P.x,
                            fmaf(g[r][1], P.y,
                            fmaf(g[r][2], P.z, P.w)));
            acc[r] += __builtin_amdgcn_exp2f(e);
        }
    }
#pragma unroll
    for (int r = 0; r < 4; ++r)
        partial[wid][r * 64 + lane] = acc[r];
    __syncthreads();

    // --- final reduce (fixed wave order, deterministic) + write diag ---
    if (t < 256) {
        const int row = chunk * 256 + t;
        if (row < NN) {
            float sum = partial[0][t];
#pragma unroll
            for (int w = 1; w < 16; ++w) sum += partial[w][t];
            const float4 Pr = Ps[row];
            const float gx = Pr.x * Gp[0][0] + Pr.y * Gp[1][0] + Pr.z * Gp[2][0];
            const float gy = Pr.x * Gp[0][1] + Pr.y * Gp[1][1] + Pr.z * Gp[2][1];
            const float gz = Pr.x * Gp[0][2] + Pr.y * Gp[1][2] + Pr.z * Gp[2][2];
            const float e  = fmaf(gx, Pr.x, fmaf(gy, Pr.y, fmaf(gz, Pr.z, Pr.w)));
            diag_out[b * NN + row] = __builtin_amdgcn_exp2f(e) / sum;
        }
    }
}

// ---------------------------------------------------------------------------
// Kernel 2: per batch — group argmax, centroid, distances, top-110 via
// histogram-select + rank-by-counting (no sort). grid 32, block 1024.
// ---------------------------------------------------------------------------
__global__ __launch_bounds__(1024) void k_select(
    const float* __restrict__ in_mat,     // [B,N,3]
    const float* __restrict__ diag,       // [B,N]
    float* __restrict__ out)              // [B,110,3]
{
    __shared__ unsigned long long keys[2048];   // 16 KB
    __shared__ unsigned long long cand[2048];   // 16 KB
    __shared__ unsigned int       hist[NBIN];   //  8 KB
    __shared__ unsigned int       sA[NBIN];     //  8 KB
    __shared__ unsigned int       sB[NBIN];     //  8 KB
    __shared__ float              wv[16];
    __shared__ int                wi_[16];
    __shared__ float              centroid[3];
    __shared__ int                thrBin, cnt;

    const int b = blockIdx.x;
    const int t = threadIdx.x;
    const float* dg  = diag + (size_t)b * NN;
    const float* inb = in_mat + (size_t)b * NN * 3;

    // zero histogram (barrier below covers it)
    hist[t] = 0u; hist[t + 1024] = 0u;
    if (t == 0) cnt = 0;

    // --- group sums (5 consecutive diag, reference order) + argmax ---
    float v = -INFINITY; int idx = 0x7fffffff;
    if (t < NN / 5) {
        float s = dg[t * 5 + 0];
        s += dg[t * 5 + 1];
        s += dg[t * 5 + 2];
        s += dg[t * 5 + 3];
        s += dg[t * 5 + 4];
        v = s; idx = t;
    }
    // wave reduce, first-max (tie -> lower index) — order-independent
#pragma unroll
    for (int off = 32; off > 0; off >>= 1) {
        const float ov = __shfl_down(v, off);
        const int   oi = __shfl_down(idx, off);
        if (ov > v || (ov == v && oi < idx)) { v = ov; idx = oi; }
    }
    if ((t & 63) == 0) { wv[t >> 6] = v; wi_[t >> 6] = idx; }
    __syncthreads();
    if (t == 0) {
        float bv = wv[0]; int bidx = wi_[0];
#pragma unroll
        for (int w = 1; w < 16; ++w) {
            if (wv[w] > bv || (wv[w] == bv && wi_[w] < bidx)) {
                bv = wv[w]; bidx = wi_[w];
            }
        }
        // centroid of winning group (bit-exact numpy mean: rn adds, /5)
        const int base = bidx * 5;
#pragma unroll
        for (int d = 0; d < 3; ++d) {
            float s = inb[(base + 0) * 3 + d];
            s = __fadd_rn(s, inb[(base + 1) * 3 + d]);
            s = __fadd_rn(s, inb[(base + 2) * 3 + d]);
            s = __fadd_rn(s, inb[(base + 3) * 3 + d]);
            s = __fadd_rn(s, inb[(base + 4) * 3 + d]);
            centroid[d] = __fdiv_rn(s, 5.0f);
        }
    }
    __syncthreads();

    const float c0 = centroid[0], c1 = centroid[1], c2 = centroid[2];

    // --- distances -> keys + histogram on dist_bits[30:20] ---
#pragma unroll
    for (int r = 0; r < 2; ++r) {
        const int n = r * 1024 + t;
        if (n < NN) {
            const float dx = inb[n * 3 + 0] - c0;
            const float dy = inb[n * 3 + 1] - c1;
            const float dz = inb[n * 3 + 2] - c2;
            // no FMA contraction: bit-exact vs np.linalg.norm ((x2+y2)+z2)
            const float d2 = __fadd_rn(__fadd_rn(__fmul_rn(dx, dx),
                                                 __fmul_rn(dy, dy)),
                                       __fmul_rn(dz, dz));
            const float dist = __fsqrt_rn(d2);
            const unsigned int db = __float_as_uint(dist);
            keys[n] = ((unsigned long long)db << 32) | (unsigned int)n;
            atomicAdd(&hist[db >> 20], 1u);   // sign=0 -> bucket < 2048
        }
    }
    __syncthreads();

    // --- inclusive scan over 2048 bins (ping-pong Hillis-Steele) ---
    unsigned int* src = hist;
    unsigned int* dst = sA;
    for (int stride = 1; stride < NBIN; stride <<= 1) {
#pragma unroll
        for (int r = 0; r < 2; ++r) {
            const int i = r * 1024 + t;
            dst[i] = src[i] + ((i >= stride) ? src[i - stride] : 0u);
        }
        __syncthreads();
        unsigned int* tmp = (dst == sA) ? sB : sA;
        src = dst; dst = (src == hist) ? sA : tmp;
    }
    const unsigned int* cum = src;

    // --- threshold bin: first bin with cum >= 110 (unique writer) ---
#pragma unroll
    for (int r = 0; r < 2; ++r) {
        const int i = r * 1024 + t;
        if (cum[i] >= TOPK_ && (i == 0 || cum[i - 1] < TOPK_)) thrBin = i;
    }
    __syncthreads();

    // --- compact candidates (all elements in bins <= thrBin) ---
    const int T = thrBin;
#pragma unroll
    for (int r = 0; r < 2; ++r) {
        const int n = r * 1024 + t;
        if (n < NN) {
            const unsigned long long k = keys[n];
            if ((int)(k >> 52) <= T) {
                const int pos = atomicAdd(&cnt, 1);
                cand[pos] = k;
            }
        }
    }
    __syncthreads();

    // --- rank-by-counting among candidates; rank == global rank ---
    const int C = cnt;
    for (int i = t; i < C; i += 1024) {
        const unsigned long long ki = cand[i];
        int rank = 0;
        for (int j = 0; j < C; ++j) rank += (cand[j] < ki);
        if (rank < TOPK_) {
            const int n = (int)(unsigned int)(ki & 0xFFFFFFFFull);
            out[((size_t)b * TOPK_ + rank) * 3 + 0] = inb[n * 3 + 0];
            out[((size_t)b * TOPK_ + rank) * 3 + 1] = inb[n * 3 + 1];
            out[((size_t)b * TOPK_ + rank) * 3 + 2] = inb[n * 3 + 2];
        }
    }
}

// ---------------------------------------------------------------------------
extern "C" void kernel_launch(void* const* d_in, const int* in_sizes, int n_in,
                              void* d_out, int out_size, void* d_ws, size_t ws_size,
                              hipStream_t stream) {
    const float* in_mat = (const float*)d_in[0];
    const float* Wi = (const float*)d_in[1];
    const float* bi = (const float*)d_in[2];
    const float* Wq = (const float*)d_in[3];
    const float* bq = (const float*)d_in[4];
    const float* Wk = (const float*)d_in[5];
    const float* bk = (const float*)d_in[6];
    // Wv, bv, Wo, bo (d_in[7..10]) are dead code in the reference.

    float* diag = (float*)d_ws;               // B*N floats = 256 KB
    float* out  = (float*)d_out;              // B*110*3 floats

    dim3 g1(8, BB);                           // (row-chunks of 256, batches)
    k_diag<<<g1, 1024, 0, stream>>>(in_mat, Wi, bi, Wq, bq, Wk, bk, diag);
    k_select<<<BB, 1024, 0, stream>>>(in_mat, diag, out);
}